// Round 6
// baseline (312.358 us; speedup 1.0000x reference)
//
#include <hip/hip_runtime.h>
#include <hip/hip_bf16.h>

#define B_ROWS 65536
#define KNUM 20
#define ZROW 5000   // extra all-zero row appended to ekf (masked-gather target)
#define NT   4      // tiles (64 rows each) per block
#define NBLK 256    // grid = 1 block per CU

typedef short  bfrag8 __attribute__((ext_vector_type(8)));  // 8 bf16 (4 VGPRs)
typedef float  facc4  __attribute__((ext_vector_type(4)));  // 4 fp32

__device__ __forceinline__ unsigned short f2bf(float f) {
    union { float f; unsigned u; } x; x.f = f;
    unsigned r = (x.u + 0x7FFFu + ((x.u >> 16) & 1u)) >> 16;   // RNE
    return (unsigned short)r;
}

// ---------------------------------------------------------------------------
// Prepack (separate launch; r4 cooperative merge failed on cross-XCD L2
// visibility): weights -> bf16 transposed [N][K]; emb_k -> f32 copy with one
// extra zeroed row at ZROW.
//   WT1: 114688 ush | WT2: 32768 | WT3: 8192 | ekf: 320064 f32 (5001 rows)
// ---------------------------------------------------------------------------
__global__ __launch_bounds__(256) void prepack(
    const float* __restrict__ W1, const float* __restrict__ W2,
    const float* __restrict__ W3, const float* __restrict__ ek,
    unsigned short* __restrict__ WT1, unsigned short* __restrict__ WT2,
    unsigned short* __restrict__ WT3, float* __restrict__ ekf)
{
    const int i = blockIdx.x * 256 + threadIdx.x;
    if (i < 114688) {                 // WT1[n*448+k] = bf16(W1[k*256+n])
        const int n = i / 448, k = i % 448;
        WT1[i] = f2bf(W1[k * 256 + n]);
    } else if (i < 147456) {          // WT2[n*256+k] = bf16(W2[k*128+n])
        const int j = i - 114688;
        WT2[j] = f2bf(W2[(j & 255) * 128 + (j >> 8)]);
    } else if (i < 155648) {          // WT3[n*128+k] = bf16(W3[k*64+n])
        const int j = i - 147456;
        WT3[j] = f2bf(W3[(j & 127) * 64 + (j >> 7)]);
    } else if (i < 475712) {          // ekf = f32 ek + zero row at ZROW
        const int j = i - 155648;
        ekf[j] = (j < 320000) ? ek[j] : 0.f;
    }
}

// ---------------------------------------------------------------------------
// ROUND-6: producer/consumer wave-specialized tile pipeline.
// 256 blocks (1/CU), 512 threads = 8 waves, 4 tiles of 64 rows per block.
// Waves 0-3 = producers: gather tile t into buf[t&1] (rows pw*16..+16,
//   4 rows per barrier segment; per row 60 ekf loads batched into v[60]).
// Waves 4-7 = consumers: GEMM1/2/3 + epilogues on tile t-1 from buf[(t&1)^1]
//   (r0-verified layouts, 4-way split: GEMM1 cols cw*64, GEMM2 cw*32,
//   GEMM3 cw*16 all rows).
// 5 phases (t=0..4); 4 barriers/phase double as consumer H1/H2 handoffs AND
// the producer->consumer Xs handoff at (D).  idx vectors for tile t+1
// prefetched one full phase ahead (idxnext -> idxcur).
// LDS 117760 B (1 block/CU):
//   buf0 [0,58368)  buf1 [58368,116736): Xs[64][456] ushort; consumed buffer
//   is reused mid-phase: H1s[64][264] at its base, H2s[64][136] at +33792.
//   tmp[64][4] float at [116736,117760).
// __launch_bounds__(512,2): VGPR cap 256 (2 waves/SIMD) -- no r1-style spill.
// Expected occupancy ~25% BY DESIGN (pipeline, not TLP, hides latency).
// ---------------------------------------------------------------------------
__global__ __launch_bounds__(512, 2) void kdmlp_fused(
    const int* __restrict__ user, const int* __restrict__ item,
    const int* __restrict__ pk, const int* __restrict__ tk, const int* __restrict__ ik,
    const int* __restrict__ vp, const int* __restrict__ vt, const int* __restrict__ vi,
    const float* __restrict__ eu, const float* __restrict__ ei,
    const unsigned short* __restrict__ WT1, const unsigned short* __restrict__ WT2,
    const unsigned short* __restrict__ WT3, const float* __restrict__ ekf,
    const float* __restrict__ b1, const float* __restrict__ b2,
    const float* __restrict__ b3, const float* __restrict__ Wp,
    const float* __restrict__ bp, float* __restrict__ out)
{
    __shared__ char smem[117760];
    float (*tmp)[4] = (float(*)[4])(smem + 116736);

    const int tid  = threadIdx.x;
    const int lane = tid & 63;
    const int wid  = tid >> 6;          // 0..7
    const int lm   = lane & 15;
    const int quad = lane >> 4;

    const bool isProd = (wid < 4);
    const int  pw = wid;                // producer wave id 0..3
    const int  cw = wid - 4;            // consumer wave id 0..3

    // producer lane->packed-index mapping (one vector load carries 60 idx)
    const int* basep = (lane < 20) ? pk : (lane < 40) ? tk : ik;
    const int  loff  = (lane < 20) ? lane
                     : (lane < 40) ? lane - 20
                     : (lane < 60) ? lane - 40 : 19;

    // consumer constants hoisted across phases (cols fixed per wave)
    float  bias1[4], bias2[2], bias3, wpv;
    bfrag8 g3b[4];
    if (!isProd) {
        #pragma unroll
        for (int nt = 0; nt < 4; ++nt) bias1[nt] = b1[cw * 64 + nt * 16 + lm];
        #pragma unroll
        for (int nt = 0; nt < 2; ++nt) bias2[nt] = b2[cw * 32 + nt * 16 + lm];
        bias3 = b3[cw * 16 + lm];
        wpv   = Wp[cw * 16 + lm];
        #pragma unroll
        for (int ks = 0; ks < 4; ++ks)
            g3b[ks] = *(const bfrag8*)(WT3 + (size_t)(cw * 16 + lm) * 128
                                           + ks * 32 + quad * 8);
    }
    const float bp0 = bp[0];

    // producer: prologue idx loads for tile 0
    int idxcur[16], idxnext[16];
    if (isProd) {
        const int m00 = blockIdx.x * NT * 64;
        #pragma unroll
        for (int rr = 0; rr < 16; ++rr)
            idxcur[rr] = basep[(size_t)(m00 + pw * 16 + rr) * KNUM + loff];
    }

// 4 rows of gather (rows pw*16 + C*4 .. +4) -- C must be a literal so all
// idxcur[] indices stay compile-time (rule: runtime-indexed reg arrays spill).
#define GATHER4(C)                                                            \
    {                                                                         \
        _Pragma("unroll")                                                     \
        for (int rr2 = 0; rr2 < 4; ++rr2) {                                   \
            const int rr = (C) * 4 + rr2;                                     \
            const int rl = pw * 16 + rr;                                      \
            const int r  = m0p + rl;                                          \
            const int u    = __builtin_amdgcn_readfirstlane(user[r]);         \
            const int itm  = __builtin_amdgcn_readfirstlane(item[r]);         \
            const int vld0 = __builtin_amdgcn_readfirstlane(vp[r]);           \
            const int vld1 = __builtin_amdgcn_readfirstlane(vt[r]);           \
            const int vld2 = __builtin_amdgcn_readfirstlane(vi[r]);           \
            float2 a = *(const float2*)(eu + (size_t)u   * 128 + 2 * lane);   \
            float2 b = *(const float2*)(ei + (size_t)itm * 128 + 2 * lane);   \
            float v[60];                                                      \
            _Pragma("unroll")                                                 \
            for (int s = 0; s < 3; ++s) {                                     \
                const int vld = (s == 0) ? vld0 : (s == 1) ? vld1 : vld2;     \
                _Pragma("unroll")                                             \
                for (int j = 0; j < KNUM; ++j) {                              \
                    int kk = __builtin_amdgcn_readlane(idxcur[rr],            \
                                                       s * KNUM + j);         \
                    kk = (j < vld) ? kk : ZROW;          /* s_cselect */      \
                    v[s * 20 + j] = ekf[(size_t)kk * 64 + lane];              \
                }                                                             \
            }                                                                 \
            ushort2 pa; pa.x = f2bf(a.x); pa.y = f2bf(a.y);                   \
            ushort2 pb; pb.x = f2bf(b.x); pb.y = f2bf(b.y);                   \
            *(ushort2*)(XsP + rl * 456 + 2 * lane)       = pa;                \
            *(ushort2*)(XsP + rl * 456 + 128 + 2 * lane) = pb;                \
            _Pragma("unroll")                                                 \
            for (int s = 0; s < 3; ++s) {                                     \
                const int vld = (s == 0) ? vld0 : (s == 1) ? vld1 : vld2;     \
                float acc0 = 0.f, acc1 = 0.f;                                 \
                _Pragma("unroll")                                             \
                for (int j = 0; j < KNUM; j += 2) {                           \
                    acc0 += v[s * 20 + j];                                    \
                    acc1 += v[s * 20 + j + 1];                                \
                }                                                             \
                const float accs = acc0 + acc1;                               \
                const float mean = (vld > 0) ? accs / (float)vld : 0.f;       \
                XsP[rl * 456 + 256 + s * 64 + lane] = f2bf(mean);             \
            }                                                                 \
        }                                                                     \
    }

    #pragma unroll 1
    for (int t = 0; t <= NT; ++t) {
        unsigned short* XsP = (unsigned short*)(smem + (size_t)(t & 1) * 58368);
        unsigned short* XsC = (unsigned short*)(smem + (size_t)((t & 1) ^ 1) * 58368);
        unsigned short* H1s = XsC;                  // stride 264 (after GEMM1)
        unsigned short* H2s = XsC + 16896;          // stride 136 (byte +33792)
        const bool prod = isProd && (t < NT);
        const bool cons = (!isProd) && (t > 0);
        const int  m0p  = (blockIdx.x * NT + t) * 64;
        const int  m0c  = (blockIdx.x * NT + t - 1) * 64;

        // producer: prefetch idx vectors for tile t+1 (consumed next phase)
        if (prod && (t + 1 < NT)) {
            const int m0n = (blockIdx.x * NT + t + 1) * 64;
            #pragma unroll
            for (int rr = 0; rr < 16; ++rr)
                idxnext[rr] = basep[(size_t)(m0n + pw * 16 + rr) * KNUM + loff];
        }

        facc4 acc1[4][4];   // spans barrier (A) into epilogue 1

        // ---------------- segment 1: GEMM1 | gather rows 0-3 ----------------
        if (cons) {
            bfrag8 g1b0[4], g1b1[4];
            #pragma unroll
            for (int nt = 0; nt < 4; ++nt)
                g1b0[nt] = *(const bfrag8*)(WT1 + (size_t)(cw * 64 + nt * 16 + lm) * 448
                                                + quad * 8);
            #pragma unroll
            for (int mt = 0; mt < 4; ++mt)
                #pragma unroll
                for (int nt = 0; nt < 4; ++nt)
                    acc1[mt][nt] = (facc4){0.f, 0.f, 0.f, 0.f};

            #pragma unroll
            for (int kp = 0; kp < 7; ++kp) {        // K = 448 = 7 * (2*32)
                const int ksA = 2 * kp, ksB = 2 * kp + 1;
                #pragma unroll
                for (int nt = 0; nt < 4; ++nt)      // prefetch ksB
                    g1b1[nt] = *(const bfrag8*)(WT1 + (size_t)(cw * 64 + nt * 16 + lm) * 448
                                                    + ksB * 32 + quad * 8);
                bfrag8 af[4];
                #pragma unroll
                for (int mt = 0; mt < 4; ++mt)
                    af[mt] = *(const bfrag8*)(XsC + (mt * 16 + lm) * 456 + ksA * 32 + quad * 8);
                #pragma unroll
                for (int mt = 0; mt < 4; ++mt)
                    #pragma unroll
                    for (int nt = 0; nt < 4; ++nt)
                        acc1[mt][nt] = __builtin_amdgcn_mfma_f32_16x16x32_bf16(
                            af[mt], g1b0[nt], acc1[mt][nt], 0, 0, 0);
                if (kp < 6) {
                    #pragma unroll
                    for (int nt = 0; nt < 4; ++nt)
                        g1b0[nt] = *(const bfrag8*)(WT1 + (size_t)(cw * 64 + nt * 16 + lm) * 448
                                                        + (ksB + 1) * 32 + quad * 8);
                }
                #pragma unroll
                for (int mt = 0; mt < 4; ++mt)
                    af[mt] = *(const bfrag8*)(XsC + (mt * 16 + lm) * 456 + ksB * 32 + quad * 8);
                #pragma unroll
                for (int mt = 0; mt < 4; ++mt)
                    #pragma unroll
                    for (int nt = 0; nt < 4; ++nt)
                        acc1[mt][nt] = __builtin_amdgcn_mfma_f32_16x16x32_bf16(
                            af[mt], g1b1[nt], acc1[mt][nt], 0, 0, 0);
            }
        }
        if (prod) GATHER4(0)
        __syncthreads();                            // (A) Xs reads done

        // ---------------- segment 2: epilogue1 | gather rows 4-7 ------------
        if (cons) {
            #pragma unroll
            for (int nt = 0; nt < 4; ++nt) {
                const int col = cw * 64 + nt * 16 + lm;
                #pragma unroll
                for (int mt = 0; mt < 4; ++mt)
                    #pragma unroll
                    for (int i = 0; i < 4; ++i) {
                        const int row = mt * 16 + quad * 4 + i;
                        H1s[row * 264 + col] =
                            f2bf(fmaxf(acc1[mt][nt][i] + bias1[nt], 0.f));
                    }
            }
        }
        if (prod) GATHER4(1)
        __syncthreads();                            // (B) H1s visible

        // ------------- segment 3: GEMM2 + epilogue2 | gather rows 8-11 ------
        if (cons) {
            facc4 acc2[4][2];
            bfrag8 g2b0[2], g2b1[2];
            #pragma unroll
            for (int nt = 0; nt < 2; ++nt)
                g2b0[nt] = *(const bfrag8*)(WT2 + (size_t)(cw * 32 + nt * 16 + lm) * 256
                                                + quad * 8);
            #pragma unroll
            for (int mt = 0; mt < 4; ++mt)
                #pragma unroll
                for (int nt = 0; nt < 2; ++nt)
                    acc2[mt][nt] = (facc4){0.f, 0.f, 0.f, 0.f};

            #pragma unroll
            for (int kp = 0; kp < 4; ++kp) {        // K = 256
                const int ksA = 2 * kp, ksB = 2 * kp + 1;
                #pragma unroll
                for (int nt = 0; nt < 2; ++nt)
                    g2b1[nt] = *(const bfrag8*)(WT2 + (size_t)(cw * 32 + nt * 16 + lm) * 256
                                                    + ksB * 32 + quad * 8);
                bfrag8 af[4];
                #pragma unroll
                for (int mt = 0; mt < 4; ++mt)
                    af[mt] = *(const bfrag8*)(H1s + (mt * 16 + lm) * 264 + ksA * 32 + quad * 8);
                #pragma unroll
                for (int mt = 0; mt < 4; ++mt)
                    #pragma unroll
                    for (int nt = 0; nt < 2; ++nt)
                        acc2[mt][nt] = __builtin_amdgcn_mfma_f32_16x16x32_bf16(
                            af[mt], g2b0[nt], acc2[mt][nt], 0, 0, 0);
                if (kp < 3) {
                    #pragma unroll
                    for (int nt = 0; nt < 2; ++nt)
                        g2b0[nt] = *(const bfrag8*)(WT2 + (size_t)(cw * 32 + nt * 16 + lm) * 256
                                                        + (ksB + 1) * 32 + quad * 8);
                }
                #pragma unroll
                for (int mt = 0; mt < 4; ++mt)
                    af[mt] = *(const bfrag8*)(H1s + (mt * 16 + lm) * 264 + ksB * 32 + quad * 8);
                #pragma unroll
                for (int mt = 0; mt < 4; ++mt)
                    #pragma unroll
                    for (int nt = 0; nt < 2; ++nt)
                        acc2[mt][nt] = __builtin_amdgcn_mfma_f32_16x16x32_bf16(
                            af[mt], g2b1[nt], acc2[mt][nt], 0, 0, 0);
            }
            // epilogue 2 -> H2s (disjoint from H1s reads)
            #pragma unroll
            for (int nt = 0; nt < 2; ++nt) {
                const int col = cw * 32 + nt * 16 + lm;
                #pragma unroll
                for (int mt = 0; mt < 4; ++mt)
                    #pragma unroll
                    for (int i = 0; i < 4; ++i) {
                        const int row = mt * 16 + quad * 4 + i;
                        H2s[row * 136 + col] =
                            f2bf(fmaxf(acc2[mt][nt][i] + bias2[nt], 0.f));
                    }
            }
        }
        if (prod) GATHER4(2)
        __syncthreads();                            // (C) H2s visible

        // ------------- segment 4: GEMM3 -> tmp | gather rows 12-15 ----------
        if (cons) {
            facc4 acc3[4];
            #pragma unroll
            for (int mt = 0; mt < 4; ++mt) acc3[mt] = (facc4){0.f, 0.f, 0.f, 0.f};
            #pragma unroll
            for (int ks = 0; ks < 4; ++ks) {        // K = 128
                bfrag8 af[4];
                #pragma unroll
                for (int mt = 0; mt < 4; ++mt)
                    af[mt] = *(const bfrag8*)(H2s + (mt * 16 + lm) * 136
                                                  + ks * 32 + quad * 8);
                #pragma unroll
                for (int mt = 0; mt < 4; ++mt)
                    acc3[mt] = __builtin_amdgcn_mfma_f32_16x16x32_bf16(
                        af[mt], g3b[ks], acc3[mt], 0, 0, 0);
            }
            #pragma unroll
            for (int mt = 0; mt < 4; ++mt)
                #pragma unroll
                for (int i = 0; i < 4; ++i) {
                    float p = fmaxf(acc3[mt][i] + bias3, 0.f) * wpv;
                    p += __shfl_xor(p, 1);
                    p += __shfl_xor(p, 2);
                    p += __shfl_xor(p, 4);
                    p += __shfl_xor(p, 8);          // sum over 16 cols (lm)
                    if (lm == 0) tmp[mt * 16 + quad * 4 + i][cw] = p;
                }
        }
        if (prod) GATHER4(3)
        __syncthreads();                            // (D) tmp + Xs_t handoff

        if (!isProd && cw == 0 && t > 0)
            out[m0c + lane] = tmp[lane][0] + tmp[lane][1]
                            + tmp[lane][2] + tmp[lane][3] + bp0;

        if (isProd && (t + 1 < NT)) {
            #pragma unroll
            for (int rr = 0; rr < 16; ++rr) idxcur[rr] = idxnext[rr];
        }
    }
#undef GATHER4
}

// ---------------------------------------------------------------------------
extern "C" void kernel_launch(void* const* d_in, const int* in_sizes, int n_in,
                              void* d_out, int out_size, void* d_ws, size_t ws_size,
                              hipStream_t stream) {
    (void)in_sizes; (void)n_in; (void)out_size; (void)ws_size;

    const int*   user = (const int*)d_in[0];
    const int*   item = (const int*)d_in[1];
    const int*   pk   = (const int*)d_in[2];
    const int*   tk   = (const int*)d_in[3];
    const int*   ik   = (const int*)d_in[4];
    const int*   vp   = (const int*)d_in[5];
    const int*   vt   = (const int*)d_in[6];
    const int*   vi   = (const int*)d_in[7];
    const float* eu   = (const float*)d_in[8];
    const float* ei   = (const float*)d_in[9];
    const float* ek   = (const float*)d_in[10];
    const float* W1   = (const float*)d_in[11];
    const float* b1   = (const float*)d_in[12];
    const float* W2   = (const float*)d_in[13];
    const float* b2   = (const float*)d_in[14];
    const float* W3   = (const float*)d_in[15];
    const float* b3   = (const float*)d_in[16];
    const float* Wp   = (const float*)d_in[17];
    const float* bp   = (const float*)d_in[18];
    float* out = (float*)d_out;

    // ws: prepacked bf16 weights + f32 emb_k(+zero row) (~1.9 MB)
    unsigned short* WT1 = (unsigned short*)d_ws;
    unsigned short* WT2 = WT1 + 114688;
    unsigned short* WT3 = WT2 + 32768;
    float*          ekf = (float*)(WT3 + 8192);   // 320064 f32 (5001 rows x 64)

    prepack<<<1859, 256, 0, stream>>>(W1, W2, W3, ek, WT1, WT2, WT3, ekf);

    kdmlp_fused<<<NBLK, 512, 0, stream>>>(
        user, item, pk, tk, ik, vp, vt, vi, eu, ei,
        WT1, WT2, WT3, ekf, b1, b2, b3, Wp, bp, out);
}

// Round 7
// 238.879 us; speedup vs baseline: 1.3076x; 1.3076x over previous
//
#include <hip/hip_runtime.h>
#include <hip/hip_bf16.h>

#define B_ROWS 65536
#define KNUM 20
#define ZROW 5000   // extra all-zero row appended to ekf (masked-gather target)

typedef short  bfrag8 __attribute__((ext_vector_type(8)));  // 8 bf16 (4 VGPRs)
typedef float  facc4  __attribute__((ext_vector_type(4)));  // 4 fp32

__device__ __forceinline__ unsigned short f2bf(float f) {
    union { float f; unsigned u; } x; x.f = f;
    unsigned r = (x.u + 0x7FFFu + ((x.u >> 16) & 1u)) >> 16;   // RNE
    return (unsigned short)r;
}

// ---------------------------------------------------------------------------
// Prepack: weights -> bf16 transposed [N][K]; emb_k -> f32 copy + zero row.
//   WT1: 114688 ush | WT2: 32768 | WT3: 8192 | ekf: 320064 f32 (5001 rows)
// ---------------------------------------------------------------------------
__global__ __launch_bounds__(256) void prepack(
    const float* __restrict__ W1, const float* __restrict__ W2,
    const float* __restrict__ W3, const float* __restrict__ ek,
    unsigned short* __restrict__ WT1, unsigned short* __restrict__ WT2,
    unsigned short* __restrict__ WT3, float* __restrict__ ekf)
{
    const int i = blockIdx.x * 256 + threadIdx.x;
    if (i < 114688) {                 // WT1[n*448+k] = bf16(W1[k*256+n])
        const int n = i / 448, k = i % 448;
        WT1[i] = f2bf(W1[k * 256 + n]);
    } else if (i < 147456) {          // WT2[n*256+k] = bf16(W2[k*128+n])
        const int j = i - 114688;
        WT2[j] = f2bf(W2[(j & 255) * 128 + (j >> 8)]);
    } else if (i < 155648) {          // WT3[n*128+k] = bf16(W3[k*64+n])
        const int j = i - 147456;
        WT3[j] = f2bf(W3[(j & 127) * 64 + (j >> 7)]);
    } else if (i < 475712) {          // ekf = f32 ek + zero row at ZROW
        const int j = i - 155648;
        ekf[j] = (j < 320000) ? ek[j] : 0.f;
    }
}

// ---------------------------------------------------------------------------
// ROUND-7a: standalone masked-mean gather kernel -> Xm[65536][192] bf16.
// No LDS, no barriers, no MFMA: waves FREE-RUN (r0-r6 showed the fused
// kernel's gather was barrier-ganged with GEMM phases; no pipe >30% busy).
// 2048 blocks x 256 thr (4 waves); each wave owns 8 rows (r3's proven
// per-row scheme: one packed idx vector load, v_readlane -> SGPR,
// s_cselect mask to ZROW, saddr f32 loads, 2-chain sum).
// (256,6): VGPR cap ~85 >> ~45 demand -- no spill; 24 waves/CU.
// WRITE_SIZE ~25.2 MB is BY DESIGN (Xm); spill tripwire is write >> 26 MB.
// ---------------------------------------------------------------------------
__global__ __launch_bounds__(256, 6) void kdmlp_gather(
    const int* __restrict__ pk, const int* __restrict__ tk,
    const int* __restrict__ ik, const int* __restrict__ vp,
    const int* __restrict__ vt, const int* __restrict__ vi,
    const float* __restrict__ ekf, unsigned short* __restrict__ Xm)
{
    const int lane = threadIdx.x & 63;
    const int gw   = blockIdx.x * 4 + (threadIdx.x >> 6);   // global wave 0..8191
    const int r0   = gw * 8;

    // lane->packed-index mapping: 0..19 pk | 20..39 tk | 40..59 ik | 60..63 dup
    const int* basep = (lane < 20) ? pk : (lane < 40) ? tk : ik;
    const int  loff  = (lane < 20) ? lane
                     : (lane < 40) ? lane - 20
                     : (lane < 60) ? lane - 40 : 19;

    int idxv[8];
    #pragma unroll
    for (int lr = 0; lr < 8; ++lr)
        idxv[lr] = basep[(size_t)(r0 + lr) * KNUM + loff];

    #pragma unroll
    for (int lr = 0; lr < 8; ++lr) {
        const int r = r0 + lr;
        const int vld0 = __builtin_amdgcn_readfirstlane(vp[r]);
        const int vld1 = __builtin_amdgcn_readfirstlane(vt[r]);
        const int vld2 = __builtin_amdgcn_readfirstlane(vi[r]);
        #pragma unroll
        for (int s = 0; s < 3; ++s) {
            const int vld = (s == 0) ? vld0 : (s == 1) ? vld1 : vld2;
            float acc0 = 0.f, acc1 = 0.f;       // 2 chains: halve add latency
            #pragma unroll
            for (int j = 0; j < KNUM; j += 2) {
                int k0 = __builtin_amdgcn_readlane(idxv[lr], s * KNUM + j);
                int k1 = __builtin_amdgcn_readlane(idxv[lr], s * KNUM + j + 1);
                k0 = (j     < vld) ? k0 : ZROW;                 // s_cselect
                k1 = (j + 1 < vld) ? k1 : ZROW;
                acc0 += ekf[(size_t)k0 * 64 + lane];            // saddr f32 load
                acc1 += ekf[(size_t)k1 * 64 + lane];
            }
            const float acc  = acc0 + acc1;
            const float mean = (vld > 0) ? acc / (float)vld : 0.f;
            Xm[(size_t)r * 192 + s * 64 + lane] = f2bf(mean);
        }
    }
}

// ---------------------------------------------------------------------------
// ROUND-7b: MLP kernel = r3 structure VERBATIM minus the ekf gather.
// Phase 0 now: eu/ei gather (2 cheap coalesced HBM loads/row) + coalesced
// Xm tile read (24 lanes x 16 B per row).  GEMM1/2/3 + epilogues unchanged
// (r3-verified layouts).  One block = 64 rows, 512 thr = 8 waves, 2 blk/CU.
// LDS 59392 B: Xs[64][456] -> H1s[64][264] @0, H2s[64][136] @33792,
//              tmp[64][4] @58368.
// ---------------------------------------------------------------------------
__global__ __launch_bounds__(512, 4) void kdmlp_mlp(
    const int* __restrict__ user, const int* __restrict__ item,
    const float* __restrict__ eu, const float* __restrict__ ei,
    const unsigned short* __restrict__ Xm,
    const unsigned short* __restrict__ WT1, const unsigned short* __restrict__ WT2,
    const unsigned short* __restrict__ WT3,
    const float* __restrict__ b1, const float* __restrict__ b2,
    const float* __restrict__ b3, const float* __restrict__ Wp,
    const float* __restrict__ bp, float* __restrict__ out)
{
    __shared__ char smem[59392];
    unsigned short* Xs  = (unsigned short*)smem;            // stride 456
    unsigned short* H1s = (unsigned short*)smem;            // stride 264
    unsigned short* H2s = (unsigned short*)(smem + 33792);  // stride 136
    float (*tmp)[4]     = (float(*)[4])(smem + 58368);

    const int tid  = threadIdx.x;
    const int lane = tid & 63;
    const int wid  = tid >> 6;          // 0..7
    const int lm   = lane & 15;
    const int quad = lane >> 4;
    const int m0   = blockIdx.x * 64;

    // ---- early issue: GEMM1 B (ks=0); completes during phase 0 ----
    bfrag8 g1b0[2], g1b1[2];
    #pragma unroll
    for (int nt = 0; nt < 2; ++nt)
        g1b0[nt] = *(const bfrag8*)(WT1 + (size_t)(wid * 32 + nt * 16 + lm) * 448
                                        + quad * 8);

    // ================= phase 0: assemble Xs from eu/ei/Xm ==================
    #pragma unroll
    for (int lr = 0; lr < 8; ++lr) {
        const int rl = wid * 8 + lr;    // local row 0..63
        const int r  = __builtin_amdgcn_readfirstlane(m0 + rl);
        const int u   = __builtin_amdgcn_readfirstlane(user[r]);
        const int itm = __builtin_amdgcn_readfirstlane(item[r]);
        float2 a = *(const float2*)(eu + (size_t)u   * 128 + 2 * lane);
        float2 b = *(const float2*)(ei + (size_t)itm * 128 + 2 * lane);
        ushort2 pa; pa.x = f2bf(a.x); pa.y = f2bf(a.y);
        ushort2 pb; pb.x = f2bf(b.x); pb.y = f2bf(b.y);
        *(ushort2*)(Xs + rl * 456 + 2 * lane)       = pa;
        *(ushort2*)(Xs + rl * 456 + 128 + 2 * lane) = pb;
        if (lane < 24)                  // 24 x 16B = 192 ush = the 3 means
            *(bfrag8*)(Xs + rl * 456 + 256 + lane * 8) =
                *(const bfrag8*)(Xm + (size_t)(m0 + rl) * 192 + lane * 8);
    }
    __syncthreads();                    // Xs complete; g1b0 resident

    // ================= GEMM1: [64,448] @ W1 -> H1 [64,256] ==================
    facc4 acc1[4][2];
    #pragma unroll
    for (int mt = 0; mt < 4; ++mt)
        #pragma unroll
        for (int nt = 0; nt < 2; ++nt)
            acc1[mt][nt] = (facc4){0.f, 0.f, 0.f, 0.f};

    #pragma unroll
    for (int kp = 0; kp < 7; ++kp) {            // K = 448 = 7 * (2*32)
        const int ksA = 2 * kp, ksB = 2 * kp + 1;
        #pragma unroll
        for (int nt = 0; nt < 2; ++nt)          // prefetch ksB
            g1b1[nt] = *(const bfrag8*)(WT1 + (size_t)(wid * 32 + nt * 16 + lm) * 448
                                            + ksB * 32 + quad * 8);
        bfrag8 af[4];
        #pragma unroll
        for (int mt = 0; mt < 4; ++mt)
            af[mt] = *(const bfrag8*)(Xs + (mt * 16 + lm) * 456 + ksA * 32 + quad * 8);
        #pragma unroll
        for (int mt = 0; mt < 4; ++mt)
            #pragma unroll
            for (int nt = 0; nt < 2; ++nt)
                acc1[mt][nt] = __builtin_amdgcn_mfma_f32_16x16x32_bf16(
                    af[mt], g1b0[nt], acc1[mt][nt], 0, 0, 0);
        if (kp < 6) {
            #pragma unroll
            for (int nt = 0; nt < 2; ++nt)      // prefetch next pair's ksA
                g1b0[nt] = *(const bfrag8*)(WT1 + (size_t)(wid * 32 + nt * 16 + lm) * 448
                                                + (ksB + 1) * 32 + quad * 8);
        }
        #pragma unroll
        for (int mt = 0; mt < 4; ++mt)
            af[mt] = *(const bfrag8*)(Xs + (mt * 16 + lm) * 456 + ksB * 32 + quad * 8);
        #pragma unroll
        for (int mt = 0; mt < 4; ++mt)
            #pragma unroll
            for (int nt = 0; nt < 2; ++nt)
                acc1[mt][nt] = __builtin_amdgcn_mfma_f32_16x16x32_bf16(
                    af[mt], g1b1[nt], acc1[mt][nt], 0, 0, 0);
    }

    // ---- early issue: GEMM2 B (ks=0) ----
    const int colw = wid * 16 + lm;             // this wave's col in GEMM2/H2
    bfrag8 g2b0 = *(const bfrag8*)(WT2 + (size_t)colw * 256 + quad * 8);
    bfrag8 g2b1;

    __syncthreads();                            // all Xs reads done

    // epilogue 1 -> H1s (C/D: col=lane&15 base, row=quad*4+reg; r3-verified)
    #pragma unroll
    for (int nt = 0; nt < 2; ++nt) {
        const int col = wid * 32 + nt * 16 + lm;
        const float bias = b1[col];
        #pragma unroll
        for (int mt = 0; mt < 4; ++mt)
            #pragma unroll
            for (int i = 0; i < 4; ++i) {
                const int row = mt * 16 + quad * 4 + i;
                H1s[row * 264 + col] = f2bf(fmaxf(acc1[mt][nt][i] + bias, 0.f));
            }
    }
    __syncthreads();

    // ================= GEMM2: [64,256] @ W2 -> H2 [64,128] ==================
    facc4 acc2[4];
    #pragma unroll
    for (int mt = 0; mt < 4; ++mt) acc2[mt] = (facc4){0.f, 0.f, 0.f, 0.f};

    #pragma unroll
    for (int kp = 0; kp < 4; ++kp) {            // K = 256 = 4 * (2*32)
        const int ksA = 2 * kp, ksB = 2 * kp + 1;
        g2b1 = *(const bfrag8*)(WT2 + (size_t)colw * 256 + ksB * 32 + quad * 8);
        bfrag8 af[4];
        #pragma unroll
        for (int mt = 0; mt < 4; ++mt)
            af[mt] = *(const bfrag8*)(H1s + (mt * 16 + lm) * 264 + ksA * 32 + quad * 8);
        #pragma unroll
        for (int mt = 0; mt < 4; ++mt)
            acc2[mt] = __builtin_amdgcn_mfma_f32_16x16x32_bf16(af[mt], g2b0, acc2[mt], 0, 0, 0);
        if (kp < 3)
            g2b0 = *(const bfrag8*)(WT2 + (size_t)colw * 256 + (ksB + 1) * 32 + quad * 8);
        #pragma unroll
        for (int mt = 0; mt < 4; ++mt)
            af[mt] = *(const bfrag8*)(H1s + (mt * 16 + lm) * 264 + ksB * 32 + quad * 8);
        #pragma unroll
        for (int mt = 0; mt < 4; ++mt)
            acc2[mt] = __builtin_amdgcn_mfma_f32_16x16x32_bf16(af[mt], g2b1, acc2[mt], 0, 0, 0);
    }

    // ---- early issue: GEMM3 B (all 4 ks) ----
    const int w3   = wid & 3;
    const int mgrp = wid >> 2;
    const int col3 = w3 * 16 + lm;
    bfrag8 g3b[4];
    #pragma unroll
    for (int ks = 0; ks < 4; ++ks)
        g3b[ks] = *(const bfrag8*)(WT3 + (size_t)col3 * 128 + ks * 32 + quad * 8);

    // epilogue 2 -> H2s (disjoint from H1s reads; barrier only after)
    {
        const float bias = b2[colw];
        #pragma unroll
        for (int mt = 0; mt < 4; ++mt)
            #pragma unroll
            for (int i = 0; i < 4; ++i) {
                const int row = mt * 16 + quad * 4 + i;
                H2s[row * 136 + colw] = f2bf(fmaxf(acc2[mt][i] + bias, 0.f));
            }
    }
    __syncthreads();

    // ========= GEMM3: [64,128] @ W3 -> relu -> dot Wp, fused reduce =========
    {
        facc4 acc3[2];
        #pragma unroll
        for (int mtl = 0; mtl < 2; ++mtl) acc3[mtl] = (facc4){0.f, 0.f, 0.f, 0.f};

        #pragma unroll
        for (int ks = 0; ks < 4; ++ks) {        // K = 128 = 4 * 32
            bfrag8 af[2];
            #pragma unroll
            for (int mtl = 0; mtl < 2; ++mtl)
                af[mtl] = *(const bfrag8*)(H2s + (mgrp * 32 + mtl * 16 + lm) * 136
                                               + ks * 32 + quad * 8);
            #pragma unroll
            for (int mtl = 0; mtl < 2; ++mtl)
                acc3[mtl] = __builtin_amdgcn_mfma_f32_16x16x32_bf16(
                    af[mtl], g3b[ks], acc3[mtl], 0, 0, 0);
        }
        const float bias = b3[col3];
        const float wpv  = Wp[col3];
        #pragma unroll
        for (int mtl = 0; mtl < 2; ++mtl)
            #pragma unroll
            for (int i = 0; i < 4; ++i) {
                float p = fmaxf(acc3[mtl][i] + bias, 0.f) * wpv;
                p += __shfl_xor(p, 1);
                p += __shfl_xor(p, 2);
                p += __shfl_xor(p, 4);
                p += __shfl_xor(p, 8);          // sum over the 16 cols (lm)
                if (lm == 0) tmp[mgrp * 32 + mtl * 16 + quad * 4 + i][w3] = p;
            }
    }
    __syncthreads();

    if (tid < 64)
        out[m0 + tid] = tmp[tid][0] + tmp[tid][1] + tmp[tid][2] + tmp[tid][3] + bp[0];
}

// ---------------------------------------------------------------------------
extern "C" void kernel_launch(void* const* d_in, const int* in_sizes, int n_in,
                              void* d_out, int out_size, void* d_ws, size_t ws_size,
                              hipStream_t stream) {
    (void)in_sizes; (void)n_in; (void)out_size; (void)ws_size;

    const int*   user = (const int*)d_in[0];
    const int*   item = (const int*)d_in[1];
    const int*   pk   = (const int*)d_in[2];
    const int*   tk   = (const int*)d_in[3];
    const int*   ik   = (const int*)d_in[4];
    const int*   vp   = (const int*)d_in[5];
    const int*   vt   = (const int*)d_in[6];
    const int*   vi   = (const int*)d_in[7];
    const float* eu   = (const float*)d_in[8];
    const float* ei   = (const float*)d_in[9];
    const float* ek   = (const float*)d_in[10];
    const float* W1   = (const float*)d_in[11];
    const float* b1   = (const float*)d_in[12];
    const float* W2   = (const float*)d_in[13];
    const float* b2   = (const float*)d_in[14];
    const float* W3   = (const float*)d_in[15];
    const float* b3   = (const float*)d_in[16];
    const float* Wp   = (const float*)d_in[17];
    const float* bp   = (const float*)d_in[18];
    float* out = (float*)d_out;

    // ws layout (26.8 MB total):
    //   WT1 114688 ush | WT2 32768 | WT3 8192 | ekf 320064 f32 | Xm 65536x192 ush
    unsigned short* WT1 = (unsigned short*)d_ws;
    unsigned short* WT2 = WT1 + 114688;
    unsigned short* WT3 = WT2 + 32768;
    float*          ekf = (float*)(WT3 + 8192);       // byte 311296
    unsigned short* Xm  = (unsigned short*)(ekf + 320064);  // byte 1591552 (16B-aligned)

    prepack<<<1859, 256, 0, stream>>>(W1, W2, W3, ek, WT1, WT2, WT3, ekf);

    kdmlp_gather<<<2048, 256, 0, stream>>>(pk, tk, ik, vp, vt, vi, ekf, Xm);

    kdmlp_mlp<<<B_ROWS / 64, 512, 0, stream>>>(
        user, item, eu, ei, Xm, WT1, WT2, WT3, b1, b2, b3, Wp, bp, out);
}